// Round 3
// baseline (552.842 us; speedup 1.0000x reference)
//
#include <hip/hip_runtime.h>

typedef __bf16 bf16x8 __attribute__((ext_vector_type(8)));
typedef float  f32x4  __attribute__((ext_vector_type(4)));

__device__ __forceinline__ float lrelu(float x, float s){ return x > 0.f ? x : s*x; }

// ---------------- dtype detection (hedge: fp32 vs bf16 storage) ----------------
__global__ void dtype_k(const unsigned* __restrict__ xw, int* __restrict__ dtf){
  if (blockIdx.x==0 && threadIdx.x==0){
    int hits = 0;
    for (int k=0; k<256; k++){
      unsigned w = xw[k];
      unsigned e = (w >> 7) & 0xFF;
      if ((w & 0x7FFFu) == 0 || (e >= 64 && e <= 160)) hits++;
    }
    *dtf = (hits >= 230) ? 1 : 0;   // 1 = bf16 storage, 0 = fp32 storage
  }
}

__global__ void cvt_bf_k(const void* __restrict__ src, __bf16* __restrict__ dst,
                         int n, const int* __restrict__ dtf){
  int t = blockIdx.x*256 + threadIdx.x;
  if (t >= n) return;
  if (*dtf) dst[t] = ((const __bf16*)src)[t];
  else      dst[t] = (__bf16)(((const float*)src)[t]);
}

__global__ void cvt_f32_k(const void* __restrict__ src, float* __restrict__ dst,
                          int n, const int* __restrict__ dtf){
  int t = blockIdx.x*256 + threadIdx.x;
  if (t >= n) return;
  if (*dtf) dst[t] = (float)((const __bf16*)src)[t];
  else      dst[t] = ((const float*)src)[t];
}

// ---------------- CSR build ----------------
__global__ void detect_k(const int* __restrict__ ei, int* __restrict__ flag){
  if (blockIdx.x==0 && threadIdx.x==0){
    int is64 = 1;
    for (int k=1; k<64; k+=2) if (ei[k] != 0){ is64 = 0; break; }
    *flag = is64;
  }
}

__global__ void zero_k(int* __restrict__ p, int n){
  int t = blockIdx.x*256 + threadIdx.x;
  if (t < n) p[t] = 0;
}

__global__ void hist_k(const int* __restrict__ ei, const int* __restrict__ flag,
                       int E, int* __restrict__ cnt){
  int t = blockIdx.x*256 + threadIdx.x;
  if (t >= E) return;
  int f = *flag;
  long di = f ? 2L*((long)E + t) : (long)(E + t);
  atomicAdd(&cnt[ei[di]], 1);
}

__global__ void scan1_k(const int* __restrict__ cnt, int* __restrict__ off,
                        int* __restrict__ bsum, int n){
  __shared__ int sc[1024];
  int t = threadIdx.x;
  int i = blockIdx.x*1024 + t;
  int v = (i < n) ? cnt[i] : 0;
  sc[t] = v; __syncthreads();
  for (int d=1; d<1024; d<<=1){
    int x = (t >= d) ? sc[t-d] : 0;
    __syncthreads();
    sc[t] += x;
    __syncthreads();
  }
  if (i < n) off[i] = sc[t] - v;          // exclusive within block
  if (t == 1023) bsum[blockIdx.x] = sc[1023];
}

__global__ void scan2_k(int* __restrict__ bsum, int nb){
  if (blockIdx.x==0 && threadIdx.x==0){
    int run = 0;
    for (int b=0; b<nb; b++){ int v = bsum[b]; bsum[b] = run; run += v; }
  }
}

__global__ void scan3_k(int* __restrict__ off, const int* __restrict__ bsum,
                        int* __restrict__ cursor, int n, int E){
  int i = blockIdx.x*1024 + threadIdx.x;
  if (i < n){
    int v = off[i] + bsum[blockIdx.x];
    off[i] = v;
    cursor[i] = v;
  }
  if (i == 0) off[n] = E;
}

__global__ void scatter_k(const int* __restrict__ ei, const int* __restrict__ flag,
                          int E, int* __restrict__ cursor, int* __restrict__ csr){
  int t = blockIdx.x*256 + threadIdx.x;
  if (t >= E) return;
  int f = *flag;
  int s = ei[f ? 2L*(long)t         : (long)t];
  int d = ei[f ? 2L*((long)E + t)   : (long)(E + t)];
  int pos = atomicAdd(&cursor[d], 1);
  csr[pos] = s;
}

// ---------------- GEMM: C[M,Ntot] = A[M,K] @ B[K,Ntot], bf16 in, fp32 out ----------------
// MFMA 16x16x32 bf16. A frag: A[m=lane&15][k=(lane>>4)*8+j]; B frag: B[k=(lane>>4)*8+j][n=lane&15];
// C/D: col=lane&15, row=(lane>>4)*4+reg.
template<int K>
__global__ __launch_bounds__(256) void gemm_k(const __bf16* __restrict__ A,
                                              const __bf16* __restrict__ B,
                                              float* __restrict__ C,
                                              int M, int Ntot){
  constexpr int KP = K + 8;                 // pad: rows stay 16B-aligned
  __shared__ __align__(16) __bf16 BT[128*KP];  // B^T slice: BT[n][k]
  const int n0 = blockIdx.y * 128;
  const int BN = min(128, Ntot - n0);
  const int tid = threadIdx.x;
  for (int idx = tid; idx < BN*K; idx += 256){
    int kk = idx / BN, nn = idx - kk*BN;
    BT[nn*KP + kk] = B[(size_t)kk*Ntot + n0 + nn];
  }
  __syncthreads();
  const int lane = tid & 63, wave = tid >> 6;
  const int row0 = (blockIdx.x*4 + wave) * 16;
  if (row0 >= M) return;
  const int m = lane & 15, kq = lane >> 4;
  bf16x8 af[K/32];
  const __bf16* Ap = A + (size_t)(row0 + m)*K + kq*8;
  #pragma unroll
  for (int ks=0; ks<K/32; ks++) af[ks] = *(const bf16x8*)(Ap + ks*32);
  const int ntc = BN >> 4;
  for (int nt=0; nt<ntc; nt++){
    f32x4 acc = {0.f, 0.f, 0.f, 0.f};
    const __bf16* Bp = &BT[(nt*16 + m)*KP + kq*8];
    #pragma unroll
    for (int ks=0; ks<K/32; ks++){
      bf16x8 bf = *(const bf16x8*)(Bp + ks*32);
      acc = __builtin_amdgcn_mfma_f32_16x16x32_bf16(af[ks], bf, acc, 0, 0, 0);
    }
    size_t cb = (size_t)(row0 + kq*4)*Ntot + (n0 + nt*16 + m);
    #pragma unroll
    for (int r=0; r<4; r++) C[cb + (size_t)r*Ntot] = acc[r];
  }
}

// ---------------- alpha_s / alpha_d row dots (fp32 h) ----------------
__global__ void alphas_k(const float* __restrict__ h, const float* __restrict__ av_s,
                         const float* __restrict__ av_d, float* __restrict__ as,
                         float* __restrict__ ad, int N, int F){
  int lane = threadIdx.x & 63;
  int row  = blockIdx.x*4 + (threadIdx.x >> 6);
  if (row >= N) return;
  float ss = 0.f, sd = 0.f;
  for (int f = lane; f < F; f += 64){
    float hv = h[(size_t)row*F + f];
    ss += hv * av_s[f];
    sd += hv * av_d[f];
  }
  for (int o=32; o>0; o>>=1){ ss += __shfl_xor(ss, o); sd += __shfl_xor(sd, o); }
  if (lane == 0){ as[row] = ss; ad[row] = sd; }
}

// ---------------- per-dst-node softmax aggregation (fp32 h -> bf16 y) ----------------
template<int F, int ACT>
__global__ __launch_bounds__(64) void aggregate_k(const float* __restrict__ h,
        const float* __restrict__ as, const float* __restrict__ ad,
        const int* __restrict__ off, const int* __restrict__ csr,
        const float* __restrict__ bias, __bf16* __restrict__ y){
  const int i = blockIdx.x;
  const int lane = threadIdx.x;
  const int beg = off[i], end = off[i+1];
  const float adi = ad[i];
  const float e_self = lrelu(as[i] + adi, 0.2f);

  // pass 1: segment max (incl. self loop)
  float mx = e_self;
  for (int p = beg + lane; p < end; p += 64)
    mx = fmaxf(mx, lrelu(as[csr[p]] + adi, 0.2f));
  for (int o=32; o>0; o>>=1) mx = fmaxf(mx, __shfl_xor(mx, o));

  // pass 2: weighted feature accumulation, chunked through LDS
  float acc0 = 0.f, acc1 = 0.f, dsum = 0.f;
  __shared__ float w_sh[64];
  __shared__ int   s_sh[64];
  for (int base = beg; base < end; base += 64){
    int p = base + lane;
    float w = 0.f; int s = 0;
    if (p < end){ s = csr[p]; w = __expf(lrelu(as[s] + adi, 0.2f) - mx); }
    w_sh[lane] = w; s_sh[lane] = s; dsum += w;
    __syncthreads();
    int cnt = min(64, end - base);
    #pragma unroll 4
    for (int k=0; k<cnt; k++){
      float wk = w_sh[k]; int sk = s_sh[k];
      if (F == 128){
        float2 hv = *(const float2*)(h + (size_t)sk*128 + 2*lane);
        acc0 += wk*hv.x; acc1 += wk*hv.y;
      } else {
        acc0 += wk * h[(size_t)sk*F + lane];
      }
    }
    __syncthreads();
  }
  for (int o=32; o>0; o>>=1) dsum += __shfl_xor(dsum, o);
  float wself = __expf(e_self - mx);
  dsum += wself;
  if (F == 128){
    float2 hv = *(const float2*)(h + (size_t)i*128 + 2*lane);
    acc0 += wself*hv.x; acc1 += wself*hv.y;
  } else {
    acc0 += wself * h[(size_t)i*F + lane];
  }
  float inv = 1.f / dsum;
  if (F == 128){
    float o0 = acc0*inv + bias[2*lane];
    float o1 = acc1*inv + bias[2*lane+1];
    if (ACT){ o0 = lrelu(o0, 0.1f); o1 = lrelu(o1, 0.1f); }
    y[(size_t)i*128 + 2*lane]     = (__bf16)o0;
    y[(size_t)i*128 + 2*lane + 1] = (__bf16)o1;
  } else {
    float o0 = acc0*inv + bias[lane];
    if (ACT) o0 = lrelu(o0, 0.1f);
    y[(size_t)i*F + lane] = (__bf16)o0;
  }
}

// ---------------- S [512,64] -> ST [64,512] (both bf16) ----------------
__global__ void transS_k(const __bf16* __restrict__ S, __bf16* __restrict__ ST,
                         int Kdim, int Nout){
  int t = blockIdx.x*256 + threadIdx.x;
  if (t < Kdim*Nout){
    int n = t / Kdim, k = t - n*Kdim;   // S[n][k], n<512 rows, k<64 cols
    ST[(size_t)k*Nout + n] = S[t];
  }
}

extern "C" void kernel_launch(void* const* d_in, const int* in_sizes, int n_in,
                              void* d_out, int out_size, void* d_ws, size_t ws_size,
                              hipStream_t stream){
  const void* x   = d_in[0];
  const int*  ei  = (const int*)d_in[1];
  const void* W1  = d_in[2];
  const void* a1s = d_in[3];
  const void* a1d = d_in[4];
  const void* b1  = d_in[5];
  const void* W2  = d_in[6];
  const void* a2s = d_in[7];
  const void* a2d = d_in[8];
  const void* b2  = d_in[9];
  const void* W3  = d_in[10];
  const void* a3s = d_in[11];
  const void* a3d = d_in[12];
  const void* b3  = d_in[13];
  const void* S   = d_in[14];
  float* out = (float*)d_out;            // reference output dtype = float32

  const int N = in_sizes[0] / 128;   // 50000
  const int E = in_sizes[1] / 2;     // 800000

  char* w = (char*)d_ws;
  size_t o = 0;
  auto alloc = [&](size_t bytes)->void*{
    void* p = w + o; o += bytes; o = (o + 255) & ~(size_t)255; return p;
  };
  int*    off    = (int*)   alloc((size_t)(N+1)*4);
  int*    cursor = (int*)   alloc((size_t)N*4);
  int*    bsum   = (int*)   alloc(64*4);
  int*    flag   = (int*)   alloc(4);
  int*    dtf    = (int*)   alloc(4);
  int*    csr    = (int*)   alloc((size_t)E*4);
  float*  as_    = (float*) alloc((size_t)N*4);
  float*  ad_    = (float*) alloc((size_t)N*4);
  float*  h      = (float*) alloc((size_t)N*128*4);
  __bf16* xb     = (__bf16*)alloc((size_t)N*128*2);
  __bf16* yb     = (__bf16*)alloc((size_t)N*128*2);
  __bf16* W1b    = (__bf16*)alloc(128*128*2);
  __bf16* W2b    = (__bf16*)alloc(128*128*2);
  __bf16* W3b    = (__bf16*)alloc(128*64*2);
  __bf16* Sb     = (__bf16*)alloc(512*64*2);
  __bf16* STb    = (__bf16*)alloc(512*64*2);
  float*  vecs   = (float*) alloc(16*128*4);
  (void)ws_size; (void)n_in; (void)out_size;

  float* a1sf = vecs + 0*128; float* a1df = vecs + 1*128; float* b1f = vecs + 2*128;
  float* a2sf = vecs + 3*128; float* a2df = vecs + 4*128; float* b2f = vecs + 5*128;
  float* a3sf = vecs + 6*128; float* a3df = vecs + 7*128; float* b3f = vecs + 8*128;

  // dtype detection + canonicalization
  dtype_k<<<1, 64, 0, stream>>>((const unsigned*)x, dtf);
  cvt_bf_k<<<(N*128+255)/256, 256, 0, stream>>>(x, xb, N*128, dtf);
  cvt_bf_k<<<(128*128+255)/256, 256, 0, stream>>>(W1, W1b, 128*128, dtf);
  cvt_bf_k<<<(128*128+255)/256, 256, 0, stream>>>(W2, W2b, 128*128, dtf);
  cvt_bf_k<<<(128*64+255)/256, 256, 0, stream>>>(W3, W3b, 128*64, dtf);
  cvt_bf_k<<<(512*64+255)/256, 256, 0, stream>>>(S, Sb, 512*64, dtf);
  cvt_f32_k<<<1, 128, 0, stream>>>(a1s, a1sf, 128, dtf);
  cvt_f32_k<<<1, 128, 0, stream>>>(a1d, a1df, 128, dtf);
  cvt_f32_k<<<1, 128, 0, stream>>>(b1,  b1f,  128, dtf);
  cvt_f32_k<<<1, 128, 0, stream>>>(a2s, a2sf, 128, dtf);
  cvt_f32_k<<<1, 128, 0, stream>>>(a2d, a2df, 128, dtf);
  cvt_f32_k<<<1, 128, 0, stream>>>(b2,  b2f,  128, dtf);
  cvt_f32_k<<<1, 64, 0, stream>>>(a3s, a3sf, 64, dtf);
  cvt_f32_k<<<1, 64, 0, stream>>>(a3d, a3df, 64, dtf);
  cvt_f32_k<<<1, 64, 0, stream>>>(b3,  b3f,  64, dtf);

  // CSR build (shared by all 3 layers)
  detect_k<<<1, 64, 0, stream>>>(ei, flag);
  zero_k<<<(N+255)/256, 256, 0, stream>>>(cursor, N);
  hist_k<<<(E+255)/256, 256, 0, stream>>>(ei, flag, E, cursor);
  int nb = (N + 1023) / 1024;
  scan1_k<<<nb, 1024, 0, stream>>>(cursor, off, bsum, N);
  scan2_k<<<1, 1, 0, stream>>>(bsum, nb);
  scan3_k<<<nb, 1024, 0, stream>>>(off, bsum, cursor, N, E);
  scatter_k<<<(E+255)/256, 256, 0, stream>>>(ei, flag, E, cursor, csr);
  transS_k<<<(512*64+255)/256, 256, 0, stream>>>(Sb, STb, 64, 512);

  const int gx = (N + 63) / 64;
  // Layer 1
  gemm_k<128><<<dim3(gx,1), 256, 0, stream>>>(xb, W1b, h, N, 128);
  alphas_k<<<(N+3)/4, 256, 0, stream>>>(h, a1sf, a1df, as_, ad_, N, 128);
  aggregate_k<128,1><<<N, 64, 0, stream>>>(h, as_, ad_, off, csr, b1f, yb);
  // Layer 2
  gemm_k<128><<<dim3(gx,1), 256, 0, stream>>>(yb, W2b, h, N, 128);
  alphas_k<<<(N+3)/4, 256, 0, stream>>>(h, a2sf, a2df, as_, ad_, N, 128);
  aggregate_k<128,1><<<N, 64, 0, stream>>>(h, as_, ad_, off, csr, b2f, yb);
  // Layer 3
  gemm_k<128><<<dim3(gx,1), 256, 0, stream>>>(yb, W3b, h, N, 64);
  alphas_k<<<(N+3)/4, 256, 0, stream>>>(h, a3sf, a3df, as_, ad_, N, 64);
  aggregate_k<64,0><<<N, 64, 0, stream>>>(h, as_, ad_, off, csr, b3f, yb);
  // Final projection: out = y @ S^T  (fp32 out)
  gemm_k<64><<<dim3(gx,4), 256, 0, stream>>>(yb, STb, out, N, 512);
}

// Round 4
// 426.559 us; speedup vs baseline: 1.2960x; 1.2960x over previous
//
#include <hip/hip_runtime.h>

typedef __bf16 bf16x8 __attribute__((ext_vector_type(8)));
typedef float  f32x4  __attribute__((ext_vector_type(4)));

__device__ __forceinline__ float lrelu(float x, float s){ return x > 0.f ? x : s*x; }

// ---------------- prep: weights fp32 -> bf16, S -> ST transpose ----------------
__global__ void prep_k(const float* __restrict__ W1, const float* __restrict__ W2,
                       const float* __restrict__ W3, const float* __restrict__ S,
                       __bf16* __restrict__ W1b, __bf16* __restrict__ W2b,
                       __bf16* __restrict__ W3b, __bf16* __restrict__ STb){
  int t = blockIdx.x*256 + threadIdx.x;
  if (t < 16384) W1b[t] = (__bf16)W1[t];
  else if (t < 32768){ int i = t-16384; W2b[i] = (__bf16)W2[i]; }
  else if (t < 40960){ int i = t-32768; W3b[i] = (__bf16)W3[i]; }
  else if (t < 73728){ int i = t-40960; int n = i>>6, k = i&63;
                       STb[(size_t)k*512 + n] = (__bf16)S[i]; }   // S[512,64] -> ST[64,512]
}

// ---------------- CSR build ----------------
__global__ void detect_k(const int* __restrict__ ei, int* __restrict__ flag){
  if (blockIdx.x==0 && threadIdx.x==0){
    int is64 = 1;
    for (int k=1; k<64; k+=2) if (ei[k] != 0){ is64 = 0; break; }
    *flag = is64;
  }
}

__global__ void zero_k(int* __restrict__ p, int n){
  int t = blockIdx.x*256 + threadIdx.x;
  if (t < n) p[t] = 0;
}

__global__ void hist_k(const int* __restrict__ ei, const int* __restrict__ flag,
                       int E, int* __restrict__ cnt){
  int t = blockIdx.x*256 + threadIdx.x;
  if (t >= E) return;
  int f = *flag;
  long di = f ? 2L*((long)E + t) : (long)(E + t);
  atomicAdd(&cnt[ei[di]], 1);
}

__global__ void scan1_k(const int* __restrict__ cnt, int* __restrict__ off,
                        int* __restrict__ bsum, int n){
  __shared__ int sc[1024];
  int t = threadIdx.x;
  int i = blockIdx.x*1024 + t;
  int v = (i < n) ? cnt[i] : 0;
  sc[t] = v; __syncthreads();
  for (int d=1; d<1024; d<<=1){
    int x = (t >= d) ? sc[t-d] : 0;
    __syncthreads();
    sc[t] += x;
    __syncthreads();
  }
  if (i < n) off[i] = sc[t] - v;
  if (t == 1023) bsum[blockIdx.x] = sc[1023];
}

// scan2 merged in: each block serially prefixes bsum[0..blockIdx.x-1] (nb<=49)
__global__ void scan3_k(int* __restrict__ off, const int* __restrict__ bsum,
                        int* __restrict__ cursor, int n, int E){
  __shared__ int base_s;
  if (threadIdx.x == 0){
    int run = 0;
    for (int b=0; b<(int)blockIdx.x; b++) run += bsum[b];
    base_s = run;
  }
  __syncthreads();
  int i = blockIdx.x*1024 + threadIdx.x;
  if (i < n){
    int v = off[i] + base_s;
    off[i] = v;
    cursor[i] = v;
  }
  if (i == 0) off[n] = E;
}

__global__ void scatter_k(const int* __restrict__ ei, const int* __restrict__ flag,
                          int E, int* __restrict__ cursor, int* __restrict__ csr){
  int t = blockIdx.x*256 + threadIdx.x;
  if (t >= E) return;
  int f = *flag;
  int s = ei[f ? 2L*(long)t         : (long)t];
  int d = ei[f ? 2L*((long)E + t)   : (long)(E + t)];
  int pos = atomicAdd(&cursor[d], 1);
  csr[pos] = s;
}

// ---------------- GEMM + fused alpha-dot epilogue ----------------
// C[M,Ntot] = A[M,K] @ B[K,Ntot]; bf16 MFMA 16x16x32, fp32 acc.
// A frag: A[m=lane&15][k=(lane>>4)*8+j]; B frag: B[k][n=lane&15];
// C/D: col=lane&15, row=(lane>>4)*4+reg.
// ALPH: also emit as_[row]=C_row . avs, ad_[row]=C_row . avd (fp32, pre-rounding).
template<int K, bool AF32, bool ALPH, bool OUTBF>
__global__ __launch_bounds__(256) void gemm_k(const __bf16* __restrict__ A,
        const float* __restrict__ Af, const __bf16* __restrict__ B,
        float* __restrict__ Cf, __bf16* __restrict__ Cb,
        const float* __restrict__ avs, const float* __restrict__ avd,
        float* __restrict__ as_, float* __restrict__ ad_,
        int M, int Ntot){
  constexpr int KP = K + 8;                    // rows stay 16B-aligned
  __shared__ __align__(16) __bf16 BT[128*KP];  // B^T slice: BT[n][k]
  const int n0 = blockIdx.y * 128;
  const int BN = min(128, Ntot - n0);
  const int tid = threadIdx.x;
  for (int idx = tid; idx < BN*K; idx += 256){
    int kk = idx / BN, nn = idx - kk*BN;
    BT[nn*KP + kk] = B[(size_t)kk*Ntot + n0 + nn];
  }
  __syncthreads();
  const int lane = tid & 63, wave = tid >> 6;
  const int row0 = (blockIdx.x*4 + wave) * 16;
  if (row0 >= M) return;
  const int m = lane & 15, kq = lane >> 4;
  bf16x8 af[K/32];
  if (AF32){
    const float* Ap = Af + (size_t)(row0 + m)*K + kq*8;
    #pragma unroll
    for (int ks=0; ks<K/32; ks++){
      f32x4 lo = *(const f32x4*)(Ap + ks*32);
      f32x4 hi = *(const f32x4*)(Ap + ks*32 + 4);
      bf16x8 v;
      #pragma unroll
      for (int j=0; j<4; j++){ v[j] = (__bf16)lo[j]; v[4+j] = (__bf16)hi[j]; }
      af[ks] = v;
    }
  } else {
    const __bf16* Ap = A + (size_t)(row0 + m)*K + kq*8;
    #pragma unroll
    for (int ks=0; ks<K/32; ks++) af[ks] = *(const bf16x8*)(Ap + ks*32);
  }
  float ps[4] = {0,0,0,0}, pd[4] = {0,0,0,0};
  const int ntc = BN >> 4;
  for (int nt=0; nt<ntc; nt++){
    f32x4 acc = {0.f, 0.f, 0.f, 0.f};
    const __bf16* Bp = &BT[(nt*16 + m)*KP + kq*8];
    #pragma unroll
    for (int ks=0; ks<K/32; ks++){
      bf16x8 bf = *(const bf16x8*)(Bp + ks*32);
      acc = __builtin_amdgcn_mfma_f32_16x16x32_bf16(af[ks], bf, acc, 0, 0, 0);
    }
    if (ALPH){
      float vs = avs[n0 + nt*16 + m], vd = avd[n0 + nt*16 + m];
      #pragma unroll
      for (int r=0; r<4; r++){ ps[r] += acc[r]*vs; pd[r] += acc[r]*vd; }
    }
    size_t cb = (size_t)(row0 + kq*4)*Ntot + (n0 + nt*16 + m);
    #pragma unroll
    for (int r=0; r<4; r++){
      if (OUTBF) Cb[cb + (size_t)r*Ntot] = (__bf16)acc[r];
      else       Cf[cb + (size_t)r*Ntot] = acc[r];
    }
  }
  if (ALPH){
    #pragma unroll
    for (int o=1; o<16; o<<=1){
      #pragma unroll
      for (int r=0; r<4; r++){ ps[r] += __shfl_xor(ps[r], o); pd[r] += __shfl_xor(pd[r], o); }
    }
    if (m == 0){
      #pragma unroll
      for (int r=0; r<4; r++){
        as_[row0 + kq*4 + r] = ps[r];
        ad_[row0 + kq*4 + r] = pd[r];
      }
    }
  }
}

// ---------------- per-dst-node softmax aggregation (bf16 h -> bf16 y) ----------------
template<int F, int ACT>
__global__ __launch_bounds__(64) void aggregate_k(const __bf16* __restrict__ h,
        const float* __restrict__ as, const float* __restrict__ ad,
        const int* __restrict__ off, const int* __restrict__ csr,
        const float* __restrict__ bias, __bf16* __restrict__ y){
  const int i = blockIdx.x;
  const int lane = threadIdx.x;
  const int beg = off[i], end = off[i+1];
  const float adi = ad[i];
  const float e_self = lrelu(as[i] + adi, 0.2f);

  // pass 1: segment max (incl. self loop); as_ is small -> L1/L2-hot gathers
  float mx = e_self;
  for (int p = beg + lane; p < end; p += 64)
    mx = fmaxf(mx, lrelu(as[csr[p]] + adi, 0.2f));
  for (int o=32; o>0; o>>=1) mx = fmaxf(mx, __shfl_xor(mx, o));

  // pass 2: weighted feature accumulation, chunked through LDS
  float acc0 = 0.f, acc1 = 0.f, dsum = 0.f;
  __shared__ float w_sh[64];
  __shared__ int   s_sh[64];
  for (int base = beg; base < end; base += 64){
    int p = base + lane;
    float w = 0.f; int s = 0;
    if (p < end){ s = csr[p]; w = __expf(lrelu(as[s] + adi, 0.2f) - mx); }
    w_sh[lane] = w; s_sh[lane] = s; dsum += w;
    __syncthreads();
    int cnt = min(64, end - base);
    #pragma unroll 8
    for (int k=0; k<cnt; k++){
      float wk = w_sh[k]; int sk = s_sh[k];
      if (F == 128){
        unsigned hv = *(const unsigned*)(h + (size_t)sk*128 + 2*lane);
        union{unsigned u; float f;} lo, hi;
        lo.u = hv << 16; hi.u = hv & 0xffff0000u;
        acc0 += wk*lo.f; acc1 += wk*hi.f;
      } else {
        acc0 += wk * (float)h[(size_t)sk*F + lane];
      }
    }
    __syncthreads();
  }
  for (int o=32; o>0; o>>=1) dsum += __shfl_xor(dsum, o);
  float wself = __expf(e_self - mx);
  dsum += wself;
  if (F == 128){
    unsigned hv = *(const unsigned*)(h + (size_t)i*128 + 2*lane);
    union{unsigned u; float f;} lo, hi;
    lo.u = hv << 16; hi.u = hv & 0xffff0000u;
    acc0 += wself*lo.f; acc1 += wself*hi.f;
  } else {
    acc0 += wself * (float)h[(size_t)i*F + lane];
  }
  float inv = 1.f / dsum;
  if (F == 128){
    float o0 = acc0*inv + bias[2*lane];
    float o1 = acc1*inv + bias[2*lane+1];
    if (ACT){ o0 = lrelu(o0, 0.1f); o1 = lrelu(o1, 0.1f); }
    y[(size_t)i*128 + 2*lane]     = (__bf16)o0;
    y[(size_t)i*128 + 2*lane + 1] = (__bf16)o1;
  } else {
    float o0 = acc0*inv + bias[lane];
    if (ACT) o0 = lrelu(o0, 0.1f);
    y[(size_t)i*F + lane] = (__bf16)o0;
  }
}

extern "C" void kernel_launch(void* const* d_in, const int* in_sizes, int n_in,
                              void* d_out, int out_size, void* d_ws, size_t ws_size,
                              hipStream_t stream){
  const float* x   = (const float*)d_in[0];
  const int*   ei  = (const int*)d_in[1];
  const float* W1  = (const float*)d_in[2];
  const float* a1s = (const float*)d_in[3];
  const float* a1d = (const float*)d_in[4];
  const float* b1  = (const float*)d_in[5];
  const float* W2  = (const float*)d_in[6];
  const float* a2s = (const float*)d_in[7];
  const float* a2d = (const float*)d_in[8];
  const float* b2  = (const float*)d_in[9];
  const float* W3  = (const float*)d_in[10];
  const float* a3s = (const float*)d_in[11];
  const float* a3d = (const float*)d_in[12];
  const float* b3  = (const float*)d_in[13];
  const float* S   = (const float*)d_in[14];
  float* out = (float*)d_out;            // fp32 output

  const int N = in_sizes[0] / 128;   // 50000
  const int E = in_sizes[1] / 2;     // 800000

  char* w = (char*)d_ws;
  size_t o = 0;
  auto alloc = [&](size_t bytes)->void*{
    void* p = w + o; o += bytes; o = (o + 255) & ~(size_t)255; return p;
  };
  int*    off    = (int*)   alloc((size_t)(N+1)*4);
  int*    cursor = (int*)   alloc((size_t)N*4);
  int*    bsum   = (int*)   alloc(64*4);
  int*    flag   = (int*)   alloc(4);
  int*    csr    = (int*)   alloc((size_t)E*4);
  float*  as_    = (float*) alloc((size_t)N*4);
  float*  ad_    = (float*) alloc((size_t)N*4);
  __bf16* hb     = (__bf16*)alloc((size_t)N*128*2);
  __bf16* yb     = (__bf16*)alloc((size_t)N*128*2);
  __bf16* W1b    = (__bf16*)alloc(128*128*2);
  __bf16* W2b    = (__bf16*)alloc(128*128*2);
  __bf16* W3b    = (__bf16*)alloc(128*64*2);
  __bf16* STb    = (__bf16*)alloc(64*512*2);
  (void)ws_size; (void)n_in; (void)out_size;

  // weight prep (1 launch)
  prep_k<<<288, 256, 0, stream>>>(W1, W2, W3, S, W1b, W2b, W3b, STb);

  // CSR build (shared by all 3 layers)
  detect_k<<<1, 64, 0, stream>>>(ei, flag);
  zero_k<<<(N+255)/256, 256, 0, stream>>>(cursor, N);
  hist_k<<<(E+255)/256, 256, 0, stream>>>(ei, flag, E, cursor);
  int nb = (N + 1023) / 1024;
  scan1_k<<<nb, 1024, 0, stream>>>(cursor, off, bsum, N);
  scan3_k<<<nb, 1024, 0, stream>>>(off, bsum, cursor, N, E);
  scatter_k<<<(E+255)/256, 256, 0, stream>>>(ei, flag, E, cursor, csr);

  const int gx = (N + 63) / 64;
  // Layer 1 (A = fp32 x)
  gemm_k<128,true,true,true><<<dim3(gx,1), 256, 0, stream>>>(
      nullptr, x, W1b, nullptr, hb, a1s, a1d, as_, ad_, N, 128);
  aggregate_k<128,1><<<N, 64, 0, stream>>>(hb, as_, ad_, off, csr, b1, yb);
  // Layer 2
  gemm_k<128,false,true,true><<<dim3(gx,1), 256, 0, stream>>>(
      yb, nullptr, W2b, nullptr, hb, a2s, a2d, as_, ad_, N, 128);
  aggregate_k<128,1><<<N, 64, 0, stream>>>(hb, as_, ad_, off, csr, b2, yb);
  // Layer 3 (Ntot = 64)
  gemm_k<128,false,true,true><<<dim3(gx,1), 256, 0, stream>>>(
      yb, nullptr, W3b, nullptr, hb, a3s, a3d, as_, ad_, N, 64);
  aggregate_k<64,0><<<N, 64, 0, stream>>>(hb, as_, ad_, off, csr, b3, yb);
  // Final projection: out[N,512] = y[N,64] @ ST[64,512]  (fp32 out)
  gemm_k<64,false,false,false><<<dim3(gx,4), 256, 0, stream>>>(
      yb, nullptr, STb, out, nullptr, nullptr, nullptr, nullptr, nullptr, N, 512);
}